// Round 2
// baseline (514.409 us; speedup 1.0000x reference)
//
#include <hip/hip_runtime.h>
#include <hip/hip_bf16.h>

#define NN 10000   // N_NODES
#define EE 32000   // N_EDGES
#define BB 16      // B
#define DD 128     // D
#define HH 8       // H
#define DH 16      // D/H
#define OUT_H_ELEMS ((size_t)NN * BB * DD)

__device__ __forceinline__ float lrelu(float x) { return x > 0.f ? x : 0.01f * x; }

// dtype-hedged load: isf32 ? f32 : bf16
__device__ __forceinline__ float ldf(const void* p, size_t i, int isf32) {
    if (isf32) return ((const float*)p)[i];
    return __bfloat162float(((const __hip_bfloat16*)p)[i]);
}
__device__ __forceinline__ void sto(void* p, size_t i, float v, int isf32) {
    if (isf32) ((float*)p)[i] = v;
    else ((__hip_bfloat16*)p)[i] = __float2bfloat16(v);
}

// ---- detect input dtype: bf16 reads of f32 data show wild exponents ----
__global__ void k_detect(const void* __restrict__ ent, int* __restrict__ flag) {
    int t = threadIdx.x;
    int hits = 0;
    for (int i = t; i < 2048; i += 256) {
        unsigned short u = ((const unsigned short*)ent)[i];
        unsigned e = (u >> 7) & 0xFF;
        if (e >= 0xC0) hits++;
    }
    if (hits) atomicAdd(flag, hits);
}

// ---- CSR by dst: count / scan / scatter ----
__global__ void k_count(const int* __restrict__ dst, int* __restrict__ cnt) {
    int e = blockIdx.x * 256 + threadIdx.x;
    if (e < EE) atomicAdd(&cnt[dst[e]], 1);
}

__global__ void k_scan(const int* __restrict__ cnt, int* __restrict__ offs) {
    __shared__ int lds[1024];
    __shared__ int carry_s;
    int tid = threadIdx.x;
    if (tid == 0) { carry_s = 0; offs[0] = 0; }
    __syncthreads();
    for (int base = 0; base < NN; base += 1024) {
        int v = (base + tid < NN) ? cnt[base + tid] : 0;
        lds[tid] = v;
        __syncthreads();
        for (int off = 1; off < 1024; off <<= 1) {
            int t = (tid >= off) ? lds[tid - off] : 0;
            __syncthreads();
            lds[tid] += t;
            __syncthreads();
        }
        int carry = carry_s;
        if (base + tid < NN) offs[base + tid + 1] = carry + lds[tid];
        __syncthreads();
        if (tid == 0) carry_s = carry + lds[1023];
        __syncthreads();
    }
}

__global__ void k_scatter(const int* __restrict__ dst, const int* __restrict__ offs,
                          int* __restrict__ cursor, int* __restrict__ csr) {
    int e = blockIdx.x * 256 + threadIdx.x;
    if (e < EE) {
        int d = dst[e];
        int p = atomicAdd(&cursor[d], 1);
        csr[offs[d] + p] = e;
    }
}

// ---- PGNN layer: h_n[n,b,d] = lrelu( (sum_e p*g_e) / (sum_e p + eps) ), e: dst==n ----
__global__ void __launch_bounds__(256) k_hn(
    const void* __restrict__ ent, const void* __restrict__ rel_emb,
    const void* __restrict__ tau_emb,
    const void* __restrict__ pgnn_i, const void* __restrict__ pgnn_j,
    const int* __restrict__ node_idx,
    const int* __restrict__ esrc, const int* __restrict__ erel, const int* __restrict__ etim,
    const int* __restrict__ btime, const int* __restrict__ offs, const int* __restrict__ csr,
    const int* __restrict__ flag, void* __restrict__ out) {
    int gid = blockIdx.x * 256 + threadIdx.x;
    if (gid >= NN * BB * DD) return;
    int isf32 = (*flag > 8);
    int d = gid & 127;
    int nb = gid >> 7;
    int b = nb & 15;
    int n = nb >> 4;
    float pj = ldf(pgnn_j, d, isf32);
    float xi_pi = ldf(ent, (size_t)node_idx[n] * DD + d, isf32) * ldf(pgnn_i, d, isf32);
    int bt = btime[b];
    int e0 = offs[n], e1 = offs[n + 1];
    float accs = 0.f, accw = 0.f;
    for (int j = e0; j < e1; ++j) {
        int e = csr[j];
        int src = esrc[e];
        int rt = erel[e]; if (rt == 0) rt = 1;
        int et = etim[e]; if (et == 0) et = 1;
        int td = et - bt; if (td < 0) td = -td;
        float g = ldf(ent, (size_t)node_idx[src] * DD + d, isf32)
                + ldf(rel_emb, (size_t)rt * DD + d, isf32)
                + ldf(tau_emb, (size_t)(td + 1) * DD + d, isf32);
        float p = __expf(lrelu(xi_pi * (g * pj)));
        accs += p;
        accw += p * g;
    }
    float hv = accw / (accs + 1e-16f);
    sto(out, gid, lrelu(hv), isf32);
}

// ---- query + g_head (tiny matmuls), one block per b ----
__global__ void k_ghead(const void* __restrict__ ent, const void* __restrict__ rel,
                        const void* __restrict__ Wc_w, const void* __restrict__ Wc_b,
                        const void* __restrict__ Wn_w, const void* __restrict__ Wn_b,
                        const int* __restrict__ head, const int* __restrict__ relation,
                        const void* __restrict__ out, const int* __restrict__ flag,
                        float* __restrict__ gh) {
    __shared__ float q[DD];
    __shared__ float hn[DD];
    int b = blockIdx.x, k = threadIdx.x;
    int isf32 = (*flag > 8);
    int hb = head[b], rb = relation[b];
    size_t eroff = (size_t)hb * DD, rroff = (size_t)rb * DD;
    size_t woff = (size_t)k * 2 * DD;
    float acc = ldf(Wc_b, k, isf32);
    for (int j = 0; j < DD; ++j) acc += ldf(ent, eroff + j, isf32) * ldf(Wc_w, woff + j, isf32);
    for (int j = 0; j < DD; ++j) acc += ldf(rel, rroff + j, isf32) * ldf(Wc_w, woff + DD + j, isf32);
    q[k] = acc;
    hn[k] = ldf(out, ((size_t)hb * BB + b) * DD + k, isf32);
    __syncthreads();
    float acc2 = ldf(Wn_b, k, isf32);
    for (int j = 0; j < DD; ++j) acc2 += hn[j] * ldf(Wn_w, woff + j, isf32);
    for (int j = 0; j < DD; ++j) acc2 += q[j] * ldf(Wn_w, woff + DD + j, isf32);
    gh[b * DD + k] = acc2;
}

// ---- per matched (e,b) pair: p[h] = exp(lrelu(t_attn)+lrelu(t_inattn)) ----
__device__ __forceinline__ void edge_p(int e, int b, int dst, int headb, int isf32,
                                       const int* erel, const int* etim, const int* btime,
                                       const void* rel_emb, const void* tau_emb,
                                       const void* ai_w, const void* aj_w,
                                       const void* iai_w, const void* iaj_w,
                                       const float* gh, const void* out,
                                       float* p) {
    int rt = erel[e]; if (rt == 0) rt = 1;
    int et = etim[e]; if (et == 0) et = 1;
    int td = et - btime[b]; if (td < 0) td = -td;
    size_t heoff = (size_t)rt * DD;
    size_t taoff = (size_t)(td + 1) * DD;
    const float* g = gh + b * DD;
    size_t hnoff = ((size_t)dst * BB + b) * DD;
    bool dh = (dst == headb);
    for (int h = 0; h < HH; ++h) {
        float sa = 0.f, si = 0.f;
        for (int kk = 0; kk < DH; ++kk) {
            int d = h * DH + kk;
            float hev = ldf(rel_emb, heoff + d, isf32);
            float tav = ldf(tau_emb, taoff + d, isf32);
            float ges = (dh ? g[d] : 0.f) + hev + tav;
            float geo = ldf(out, hnoff + d, isf32) + hev + tav;
            sa += (g[d] * ldf(ai_w, d, isf32)) * (ges * ldf(aj_w, d, isf32));
            si += (g[d] * ldf(iai_w, d, isf32)) * (geo * ldf(iaj_w, d, isf32));
        }
        p[h] = __expf(lrelu(sa) + lrelu(si));
    }
}

// ---- denominators: sum of exp(score2) over edges with src==head[b] ----
__global__ void k_s1(const int* __restrict__ esrc, const int* __restrict__ edst,
                     const int* __restrict__ erel, const int* __restrict__ etim,
                     const int* __restrict__ head, const int* __restrict__ btime,
                     const void* __restrict__ rel_emb, const void* __restrict__ tau_emb,
                     const void* __restrict__ ai_w, const void* __restrict__ aj_w,
                     const void* __restrict__ iai_w, const void* __restrict__ iaj_w,
                     const float* __restrict__ gh, const void* __restrict__ out,
                     const int* __restrict__ flag, float* __restrict__ denom) {
    int t = blockIdx.x * 256 + threadIdx.x;
    if (t >= EE * BB) return;
    int e = t >> 4, b = t & 15;
    if (esrc[e] != head[b]) return;
    int isf32 = (*flag > 8);
    float p[HH];
    edge_p(e, b, edst[e], head[b], isf32, erel, etim, btime, rel_emb, tau_emb,
           ai_w, aj_w, iai_w, iaj_w, gh, out, p);
    for (int h = 0; h < HH; ++h) atomicAdd(&denom[b * HH + h], p[h]);
}

// ---- a_new[n,b,h] = sum over dst-CSR edges of n with src==head[b] of p/denom ----
__global__ void k_anew(const int* __restrict__ esrc,
                       const int* __restrict__ erel, const int* __restrict__ etim,
                       const int* __restrict__ head, const int* __restrict__ btime,
                       const void* __restrict__ rel_emb, const void* __restrict__ tau_emb,
                       const void* __restrict__ ai_w, const void* __restrict__ aj_w,
                       const void* __restrict__ iai_w, const void* __restrict__ iaj_w,
                       const float* __restrict__ gh, const int* __restrict__ offs,
                       const int* __restrict__ csr, const int* __restrict__ flag,
                       const float* __restrict__ denom, void* __restrict__ out) {
    int t = blockIdx.x * 256 + threadIdx.x;
    if (t >= NN * BB) return;
    int b = t & 15;
    int n = t >> 4;
    int isf32 = (*flag > 8);
    int hb = head[b];
    float acc[HH];
    for (int h = 0; h < HH; ++h) acc[h] = 0.f;
    int e0 = offs[n], e1 = offs[n + 1];
    for (int j = e0; j < e1; ++j) {
        int e = csr[j];
        if (esrc[e] != hb) continue;
        float p[HH];
        edge_p(e, b, n, hb, isf32, erel, etim, btime, rel_emb, tau_emb,
               ai_w, aj_w, iai_w, iaj_w, gh, out, p);
        for (int h = 0; h < HH; ++h) acc[h] += p[h] / (denom[b * HH + h] + 1e-16f);
    }
    size_t base = OUT_H_ELEMS + (size_t)t * HH;
    for (int h = 0; h < HH; ++h) sto(out, base + h, acc[h], isf32);
}

extern "C" void kernel_launch(void* const* d_in, const int* in_sizes, int n_in,
                              void* d_out, int out_size, void* d_ws, size_t ws_size,
                              hipStream_t stream) {
    const void* ent   = d_in[0];
    const void* rel   = d_in[1];
    const void* tau   = d_in[2];
    const void* Wc_w  = d_in[3];
    const void* Wc_b  = d_in[4];
    const void* Wn_w  = d_in[5];
    const void* Wn_b  = d_in[6];
    const void* ai_w  = d_in[7];
    const void* aj_w  = d_in[8];
    const void* iai_w = d_in[9];
    const void* iaj_w = d_in[10];
    const void* pi_w  = d_in[11];
    const void* pj_w  = d_in[12];
    const int* node_idx = (const int*)d_in[13];
    const int* esrc     = (const int*)d_in[14];
    const int* edst     = (const int*)d_in[15];
    const int* erel     = (const int*)d_in[16];
    const int* etim     = (const int*)d_in[17];
    const int* head     = (const int*)d_in[18];
    const int* relation = (const int*)d_in[19];
    const int* btime    = (const int*)d_in[20];

    char* ws = (char*)d_ws;
    size_t o = 0;
    auto alloc = [&](size_t bytes) -> char* {
        char* p = ws + o;
        o += (bytes + 255) & ~(size_t)255;
        return p;
    };
    int* flag     = (int*)alloc(4);               // zeroed
    int* cnt      = (int*)alloc(NN * 4);          // zeroed (adjacent to flag)
    int* cursor   = (int*)alloc(NN * 4);          // zeroed (adjacent to cnt)
    int* offs     = (int*)alloc((NN + 1) * 4);
    int* csr      = (int*)alloc(EE * 4);
    float* gh     = (float*)alloc(BB * DD * 4);
    float* denom  = (float*)alloc(BB * HH * 4);   // zeroed
    // total ws usage ~252 KB

    size_t cnt_pad = (NN * 4 + 255) & ~(size_t)255;
    hipMemsetAsync(flag, 0, 256 + cnt_pad * 2, stream);   // flag + cnt + cursor
    hipMemsetAsync(denom, 0, BB * HH * 4, stream);

    k_detect<<<1, 256, 0, stream>>>(ent, flag);
    k_count<<<(EE + 255) / 256, 256, 0, stream>>>(edst, cnt);
    k_scan<<<1, 1024, 0, stream>>>(cnt, offs);
    k_scatter<<<(EE + 255) / 256, 256, 0, stream>>>(edst, offs, cursor, csr);

    k_hn<<<(NN * BB * DD + 255) / 256, 256, 0, stream>>>(
        ent, rel, tau, pi_w, pj_w, node_idx, esrc, erel, etim, btime, offs, csr, flag, d_out);

    k_ghead<<<BB, DD, 0, stream>>>(ent, rel, Wc_w, Wc_b, Wn_w, Wn_b,
                                   head, relation, d_out, flag, gh);

    k_s1<<<(EE * BB + 255) / 256, 256, 0, stream>>>(
        esrc, edst, erel, etim, head, btime, rel, tau,
        ai_w, aj_w, iai_w, iaj_w, gh, d_out, flag, denom);

    k_anew<<<(NN * BB + 255) / 256, 256, 0, stream>>>(
        esrc, erel, etim, head, btime, rel, tau,
        ai_w, aj_w, iai_w, iaj_w, gh, offs, csr, flag, denom, d_out);
}

// Round 3
// 418.446 us; speedup vs baseline: 1.2293x; 1.2293x over previous
//
#include <hip/hip_runtime.h>
#include <hip/hip_bf16.h>

#define NN 10000   // N_NODES
#define EE 32000   // N_EDGES
#define BB 16      // B
#define DD 128     // D
#define HH 8       // H
#define DH 16      // D/H
#define CHUNK 32   // edges staged per LDS pass in k_hn
#define OUT_H_ELEMS ((size_t)NN * BB * DD)

__device__ __forceinline__ float lrelu(float x) { return x > 0.f ? x : 0.01f * x; }

// dtype-hedged load: isf32 ? f32 : bf16
__device__ __forceinline__ float ldf(const void* p, size_t i, int isf32) {
    if (isf32) return ((const float*)p)[i];
    return __bfloat162float(((const __hip_bfloat16*)p)[i]);
}
__device__ __forceinline__ void sto(void* p, size_t i, float v, int isf32) {
    if (isf32) ((float*)p)[i] = v;
    else ((__hip_bfloat16*)p)[i] = __float2bfloat16(v);
}

// ---- detect input dtype: bf16 reads of f32 data show wild exponents ----
__global__ void k_detect(const void* __restrict__ ent, int* __restrict__ flag) {
    int t = threadIdx.x;
    int hits = 0;
    for (int i = t; i < 2048; i += 256) {
        unsigned short u = ((const unsigned short*)ent)[i];
        unsigned e = (u >> 7) & 0xFF;
        if (e >= 0xC0) hits++;
    }
    if (hits) atomicAdd(flag, hits);
}

// ---- CSR by dst: count / scan / scatter ----
__global__ void k_count(const int* __restrict__ dst, int* __restrict__ cnt) {
    int e = blockIdx.x * 256 + threadIdx.x;
    if (e < EE) atomicAdd(&cnt[dst[e]], 1);
}

__global__ void k_scan(const int* __restrict__ cnt, int* __restrict__ offs) {
    __shared__ int lds[1024];
    __shared__ int carry_s;
    int tid = threadIdx.x;
    if (tid == 0) { carry_s = 0; offs[0] = 0; }
    __syncthreads();
    for (int base = 0; base < NN; base += 1024) {
        int v = (base + tid < NN) ? cnt[base + tid] : 0;
        lds[tid] = v;
        __syncthreads();
        for (int off = 1; off < 1024; off <<= 1) {
            int t = (tid >= off) ? lds[tid - off] : 0;
            __syncthreads();
            lds[tid] += t;
            __syncthreads();
        }
        int carry = carry_s;
        if (base + tid < NN) offs[base + tid + 1] = carry + lds[tid];
        __syncthreads();
        if (tid == 0) carry_s = carry + lds[1023];
        __syncthreads();
    }
}

__global__ void k_scatter(const int* __restrict__ dst, const int* __restrict__ offs,
                          int* __restrict__ cursor, int* __restrict__ csr) {
    int e = blockIdx.x * 256 + threadIdx.x;
    if (e < EE) {
        int d = dst[e];
        int p = atomicAdd(&cursor[d], 1);
        csr[offs[d] + p] = e;
    }
}

// ---- PGNN layer, node-per-block ----
// h_n[n,b,d] = lrelu( (sum_e p*g_e) / (sum_e p + eps) ), e: dst==n
// Stage per-edge scalars + er[j][d]=ent[ni[src]][d]+rel[rt][d] in LDS once;
// each thread owns d=tid&127 and 8 of the 16 batches.
__global__ void __launch_bounds__(256) k_hn(
    const void* __restrict__ ent, const void* __restrict__ rel_emb,
    const void* __restrict__ tau_emb,
    const void* __restrict__ pgnn_i, const void* __restrict__ pgnn_j,
    const int* __restrict__ node_idx,
    const int* __restrict__ esrc, const int* __restrict__ erel, const int* __restrict__ etim,
    const int* __restrict__ btime, const int* __restrict__ offs, const int* __restrict__ csr,
    const int* __restrict__ flag, void* __restrict__ out) {
    __shared__ float er_l[CHUNK * DD];
    __shared__ int srcni_l[CHUNK];
    __shared__ int rt_l[CHUNK];
    __shared__ int et_l[CHUNK];

    int n = blockIdx.x;
    int tid = threadIdx.x;
    int isf32 = (*flag > 8);
    int d = tid & 127;
    int bh = tid >> 7;            // 0 or 1: covers b = bh*8 + bi

    int ni = node_idx[n];
    float xi = ldf(ent, (size_t)ni * DD + d, isf32) * ldf(pgnn_i, d, isf32);
    float pjv = ldf(pgnn_j, d, isf32);

    int bt_r[8];
#pragma unroll
    for (int bi = 0; bi < 8; ++bi) bt_r[bi] = btime[bh * 8 + bi];

    float accs[8], accw[8];
#pragma unroll
    for (int bi = 0; bi < 8; ++bi) { accs[bi] = 0.f; accw[bi] = 0.f; }

    int e0 = offs[n];
    int deg = offs[n + 1] - e0;

    for (int cb = 0; cb < deg; cb += CHUNK) {
        int cd = deg - cb; if (cd > CHUNK) cd = CHUNK;
        // phase 1: per-edge scalars
        for (int j = tid; j < cd; j += 256) {
            int e = csr[e0 + cb + j];
            srcni_l[j] = node_idx[esrc[e]];
            int rt = erel[e]; if (rt == 0) rt = 1;
            rt_l[j] = rt;
            int et = etim[e]; if (et == 0) et = 1;
            et_l[j] = et;
        }
        __syncthreads();
        // phase 2: er = ent[ni_src] + rel[rt]
        for (int idx = tid; idx < cd * DD; idx += 256) {
            int j = idx >> 7, dd = idx & 127;
            er_l[idx] = ldf(ent, (size_t)srcni_l[j] * DD + dd, isf32)
                      + ldf(rel_emb, (size_t)rt_l[j] * DD + dd, isf32);
        }
        __syncthreads();
        // phase 3: accumulate
        for (int j = 0; j < cd; ++j) {
            float erv = er_l[j * DD + d];
            int et = et_l[j];
#pragma unroll
            for (int bi = 0; bi < 8; ++bi) {
                int td = et - bt_r[bi]; if (td < 0) td = -td;
                float tv = ldf(tau_emb, ((size_t)(td + 1) << 7) + d, isf32);
                float g = erv + tv;
                float sc = xi * (g * pjv);
                float p = __expf(sc > 0.f ? sc : 0.01f * sc);
                accs[bi] += p;
                accw[bi] = fmaf(p, g, accw[bi]);
            }
        }
        __syncthreads();
    }

#pragma unroll
    for (int bi = 0; bi < 8; ++bi) {
        float hv = accw[bi] / (accs[bi] + 1e-16f);
        int b = bh * 8 + bi;
        sto(out, ((size_t)n * BB + b) * DD + d, lrelu(hv), isf32);
    }
}

// ---- query + g_head (tiny matmuls), one block per b ----
__global__ void k_ghead(const void* __restrict__ ent, const void* __restrict__ rel,
                        const void* __restrict__ Wc_w, const void* __restrict__ Wc_b,
                        const void* __restrict__ Wn_w, const void* __restrict__ Wn_b,
                        const int* __restrict__ head, const int* __restrict__ relation,
                        const void* __restrict__ out, const int* __restrict__ flag,
                        float* __restrict__ gh) {
    __shared__ float q[DD];
    __shared__ float hn[DD];
    int b = blockIdx.x, k = threadIdx.x;
    int isf32 = (*flag > 8);
    int hb = head[b], rb = relation[b];
    size_t eroff = (size_t)hb * DD, rroff = (size_t)rb * DD;
    size_t woff = (size_t)k * 2 * DD;
    float acc = ldf(Wc_b, k, isf32);
    for (int j = 0; j < DD; ++j) acc += ldf(ent, eroff + j, isf32) * ldf(Wc_w, woff + j, isf32);
    for (int j = 0; j < DD; ++j) acc += ldf(rel, rroff + j, isf32) * ldf(Wc_w, woff + DD + j, isf32);
    q[k] = acc;
    hn[k] = ldf(out, ((size_t)hb * BB + b) * DD + k, isf32);
    __syncthreads();
    float acc2 = ldf(Wn_b, k, isf32);
    for (int j = 0; j < DD; ++j) acc2 += hn[j] * ldf(Wn_w, woff + j, isf32);
    for (int j = 0; j < DD; ++j) acc2 += q[j] * ldf(Wn_w, woff + DD + j, isf32);
    gh[b * DD + k] = acc2;
}

// ---- per matched (e,b) pair: p[h] = exp(lrelu(t_attn)+lrelu(t_inattn)) ----
__device__ __forceinline__ void edge_p(int e, int b, int dst, int headb, int isf32,
                                       const int* erel, const int* etim, const int* btime,
                                       const void* rel_emb, const void* tau_emb,
                                       const void* ai_w, const void* aj_w,
                                       const void* iai_w, const void* iaj_w,
                                       const float* gh, const void* out,
                                       float* p) {
    int rt = erel[e]; if (rt == 0) rt = 1;
    int et = etim[e]; if (et == 0) et = 1;
    int td = et - btime[b]; if (td < 0) td = -td;
    size_t heoff = (size_t)rt * DD;
    size_t taoff = (size_t)(td + 1) * DD;
    const float* g = gh + b * DD;
    size_t hnoff = ((size_t)dst * BB + b) * DD;
    bool dh = (dst == headb);
    for (int h = 0; h < HH; ++h) {
        float sa = 0.f, si = 0.f;
        for (int kk = 0; kk < DH; ++kk) {
            int d = h * DH + kk;
            float hev = ldf(rel_emb, heoff + d, isf32);
            float tav = ldf(tau_emb, taoff + d, isf32);
            float ges = (dh ? g[d] : 0.f) + hev + tav;
            float geo = ldf(out, hnoff + d, isf32) + hev + tav;
            sa += (g[d] * ldf(ai_w, d, isf32)) * (ges * ldf(aj_w, d, isf32));
            si += (g[d] * ldf(iai_w, d, isf32)) * (geo * ldf(iaj_w, d, isf32));
        }
        p[h] = __expf(lrelu(sa) + lrelu(si));
    }
}

// ---- denominators: one thread per edge, loop over b ----
__global__ void k_s1(const int* __restrict__ esrc, const int* __restrict__ edst,
                     const int* __restrict__ erel, const int* __restrict__ etim,
                     const int* __restrict__ head, const int* __restrict__ btime,
                     const void* __restrict__ rel_emb, const void* __restrict__ tau_emb,
                     const void* __restrict__ ai_w, const void* __restrict__ aj_w,
                     const void* __restrict__ iai_w, const void* __restrict__ iaj_w,
                     const float* __restrict__ gh, const void* __restrict__ out,
                     const int* __restrict__ flag, float* __restrict__ denom) {
    __shared__ int head_l[BB];
    if (threadIdx.x < BB) head_l[threadIdx.x] = head[threadIdx.x];
    __syncthreads();
    int e = blockIdx.x * 256 + threadIdx.x;
    if (e >= EE) return;
    int s = esrc[e];
    int isf32 = (*flag > 8);
    for (int b = 0; b < BB; ++b) {
        if (head_l[b] != s) continue;
        float p[HH];
        edge_p(e, b, edst[e], s, isf32, erel, etim, btime, rel_emb, tau_emb,
               ai_w, aj_w, iai_w, iaj_w, gh, out, p);
        for (int h = 0; h < HH; ++h) atomicAdd(&denom[b * HH + h], p[h]);
    }
}

// ---- a_new[n,b,h] = sum over dst-CSR edges of n with src==head[b] of p/denom ----
__global__ void k_anew(const int* __restrict__ esrc,
                       const int* __restrict__ erel, const int* __restrict__ etim,
                       const int* __restrict__ head, const int* __restrict__ btime,
                       const void* __restrict__ rel_emb, const void* __restrict__ tau_emb,
                       const void* __restrict__ ai_w, const void* __restrict__ aj_w,
                       const void* __restrict__ iai_w, const void* __restrict__ iaj_w,
                       const float* __restrict__ gh, const int* __restrict__ offs,
                       const int* __restrict__ csr, const int* __restrict__ flag,
                       const float* __restrict__ denom, void* __restrict__ out) {
    int t = blockIdx.x * 256 + threadIdx.x;
    if (t >= NN * BB) return;
    int b = t & 15;
    int n = t >> 4;
    int isf32 = (*flag > 8);
    int hb = head[b];
    float acc[HH];
    for (int h = 0; h < HH; ++h) acc[h] = 0.f;
    int e0 = offs[n], e1 = offs[n + 1];
    for (int j = e0; j < e1; ++j) {
        int e = csr[j];
        if (esrc[e] != hb) continue;
        float p[HH];
        edge_p(e, b, n, hb, isf32, erel, etim, btime, rel_emb, tau_emb,
               ai_w, aj_w, iai_w, iaj_w, gh, out, p);
        for (int h = 0; h < HH; ++h) acc[h] += p[h] / (denom[b * HH + h] + 1e-16f);
    }
    size_t base = OUT_H_ELEMS + (size_t)t * HH;
    for (int h = 0; h < HH; ++h) sto(out, base + h, acc[h], isf32);
}

extern "C" void kernel_launch(void* const* d_in, const int* in_sizes, int n_in,
                              void* d_out, int out_size, void* d_ws, size_t ws_size,
                              hipStream_t stream) {
    const void* ent   = d_in[0];
    const void* rel   = d_in[1];
    const void* tau   = d_in[2];
    const void* Wc_w  = d_in[3];
    const void* Wc_b  = d_in[4];
    const void* Wn_w  = d_in[5];
    const void* Wn_b  = d_in[6];
    const void* ai_w  = d_in[7];
    const void* aj_w  = d_in[8];
    const void* iai_w = d_in[9];
    const void* iaj_w = d_in[10];
    const void* pi_w  = d_in[11];
    const void* pj_w  = d_in[12];
    const int* node_idx = (const int*)d_in[13];
    const int* esrc     = (const int*)d_in[14];
    const int* edst     = (const int*)d_in[15];
    const int* erel     = (const int*)d_in[16];
    const int* etim     = (const int*)d_in[17];
    const int* head     = (const int*)d_in[18];
    const int* relation = (const int*)d_in[19];
    const int* btime    = (const int*)d_in[20];

    char* ws = (char*)d_ws;
    size_t o = 0;
    auto alloc = [&](size_t bytes) -> char* {
        char* p = ws + o;
        o += (bytes + 255) & ~(size_t)255;
        return p;
    };
    int* flag     = (int*)alloc(4);               // zeroed
    int* cnt      = (int*)alloc(NN * 4);          // zeroed (adjacent to flag)
    int* cursor   = (int*)alloc(NN * 4);          // zeroed (adjacent to cnt)
    int* offs     = (int*)alloc((NN + 1) * 4);
    int* csr      = (int*)alloc(EE * 4);
    float* gh     = (float*)alloc(BB * DD * 4);
    float* denom  = (float*)alloc(BB * HH * 4);   // zeroed
    // total ws usage ~252 KB

    size_t cnt_pad = (NN * 4 + 255) & ~(size_t)255;
    hipMemsetAsync(flag, 0, 256 + cnt_pad * 2, stream);   // flag + cnt + cursor
    hipMemsetAsync(denom, 0, BB * HH * 4, stream);

    k_detect<<<1, 256, 0, stream>>>(ent, flag);
    k_count<<<(EE + 255) / 256, 256, 0, stream>>>(edst, cnt);
    k_scan<<<1, 1024, 0, stream>>>(cnt, offs);
    k_scatter<<<(EE + 255) / 256, 256, 0, stream>>>(edst, offs, cursor, csr);

    k_hn<<<NN, 256, 0, stream>>>(
        ent, rel, tau, pi_w, pj_w, node_idx, esrc, erel, etim, btime, offs, csr, flag, d_out);

    k_ghead<<<BB, DD, 0, stream>>>(ent, rel, Wc_w, Wc_b, Wn_w, Wn_b,
                                   head, relation, d_out, flag, gh);

    k_s1<<<(EE + 255) / 256, 256, 0, stream>>>(
        esrc, edst, erel, etim, head, btime, rel, tau,
        ai_w, aj_w, iai_w, iaj_w, gh, d_out, flag, denom);

    k_anew<<<(NN * BB + 255) / 256, 256, 0, stream>>>(
        esrc, erel, etim, head, btime, rel, tau,
        ai_w, aj_w, iai_w, iaj_w, gh, offs, csr, flag, denom, d_out);
}

// Round 4
// 259.548 us; speedup vs baseline: 1.9819x; 1.6122x over previous
//
#include <hip/hip_runtime.h>
#include <hip/hip_bf16.h>

#define NN 10000   // N_NODES
#define EE 32000   // N_EDGES
#define BB 16      // B
#define DD 128     // D
#define HH 8       // H
#define DH 16      // D/H
#define CHUNK 32   // edges staged per LDS pass in k_hn
#define MAXP 4096  // max matched (edge,batch) pairs (expected ~51)
#define OUT_H_ELEMS ((size_t)NN * BB * DD)

__device__ __forceinline__ float lrelu(float x) { return x > 0.f ? x : 0.01f * x; }

// dtype-hedged load: isf32 ? f32 : bf16
__device__ __forceinline__ float ldf(const void* p, size_t i, int isf32) {
    if (isf32) return ((const float*)p)[i];
    return __bfloat162float(((const __hip_bfloat16*)p)[i]);
}
__device__ __forceinline__ void sto(void* p, size_t i, float v, int isf32) {
    if (isf32) ((float*)p)[i] = v;
    else ((__hip_bfloat16*)p)[i] = __float2bfloat16(v);
}

__device__ void atomicAddF(void* out, size_t i, float v, int isf32) {
    if (isf32) { atomicAdd((float*)out + i, v); return; }
    // bf16 CAS fallback (not expected to be exercised)
    __hip_bfloat16* addr = (__hip_bfloat16*)out + i;
    unsigned* base = (unsigned*)((size_t)addr & ~(size_t)3);
    bool hi = ((size_t)addr & 2) != 0;
    unsigned old = *base, assumed;
    do {
        assumed = old;
        unsigned short cur = hi ? (unsigned short)(assumed >> 16) : (unsigned short)(assumed & 0xFFFF);
        __hip_bfloat16 c = *(__hip_bfloat16*)&cur;
        __hip_bfloat16 nh = __float2bfloat16(__bfloat162float(c) + v);
        unsigned short nb = *(unsigned short*)&nh;
        unsigned nw = hi ? ((assumed & 0xFFFFu) | ((unsigned)nb << 16))
                         : ((assumed & 0xFFFF0000u) | nb);
        old = atomicCAS(base, assumed, nw);
    } while (old != assumed);
}

// ---- detect input dtype: bf16 reads of f32 data show wild exponents ----
__global__ void k_detect(const void* __restrict__ ent, int* __restrict__ flag) {
    int t = threadIdx.x;
    int hits = 0;
    for (int i = t; i < 2048; i += 256) {
        unsigned short u = ((const unsigned short*)ent)[i];
        unsigned e = (u >> 7) & 0xFF;
        if (e >= 0xC0) hits++;
    }
    if (hits) atomicAdd(flag, hits);
}

// ---- CSR by dst: count / scan / scatter ----
__global__ void k_count(const int* __restrict__ dst, int* __restrict__ cnt) {
    int e = blockIdx.x * 256 + threadIdx.x;
    if (e < EE) atomicAdd(&cnt[dst[e]], 1);
}

__global__ void k_scan(const int* __restrict__ cnt, int* __restrict__ offs) {
    __shared__ int lds[1024];
    __shared__ int carry_s;
    int tid = threadIdx.x;
    if (tid == 0) { carry_s = 0; offs[0] = 0; }
    __syncthreads();
    for (int base = 0; base < NN; base += 1024) {
        int v = (base + tid < NN) ? cnt[base + tid] : 0;
        lds[tid] = v;
        __syncthreads();
        for (int off = 1; off < 1024; off <<= 1) {
            int t = (tid >= off) ? lds[tid - off] : 0;
            __syncthreads();
            lds[tid] += t;
            __syncthreads();
        }
        int carry = carry_s;
        if (base + tid < NN) offs[base + tid + 1] = carry + lds[tid];
        __syncthreads();
        if (tid == 0) carry_s = carry + lds[1023];
        __syncthreads();
    }
}

__global__ void k_scatter(const int* __restrict__ dst, const int* __restrict__ offs,
                          int* __restrict__ cursor, int* __restrict__ csr) {
    int e = blockIdx.x * 256 + threadIdx.x;
    if (e < EE) {
        int d = dst[e];
        int p = atomicAdd(&cursor[d], 1);
        csr[offs[d] + p] = e;
    }
}

// ---- PGNN layer, node-per-block ----
__global__ void __launch_bounds__(256) k_hn(
    const void* __restrict__ ent, const void* __restrict__ rel_emb,
    const void* __restrict__ tau_emb,
    const void* __restrict__ pgnn_i, const void* __restrict__ pgnn_j,
    const int* __restrict__ node_idx,
    const int* __restrict__ esrc, const int* __restrict__ erel, const int* __restrict__ etim,
    const int* __restrict__ btime, const int* __restrict__ offs, const int* __restrict__ csr,
    const int* __restrict__ flag, void* __restrict__ out) {
    __shared__ float er_l[CHUNK * DD];
    __shared__ int srcni_l[CHUNK];
    __shared__ int rt_l[CHUNK];
    __shared__ int et_l[CHUNK];

    int n = blockIdx.x;
    int tid = threadIdx.x;
    int isf32 = (*flag > 8);
    int d = tid & 127;
    int bh = tid >> 7;            // 0 or 1: covers b = bh*8 + bi

    int ni = node_idx[n];
    float xi = ldf(ent, (size_t)ni * DD + d, isf32) * ldf(pgnn_i, d, isf32);
    float pjv = ldf(pgnn_j, d, isf32);

    int bt_r[8];
#pragma unroll
    for (int bi = 0; bi < 8; ++bi) bt_r[bi] = btime[bh * 8 + bi];

    float accs[8], accw[8];
#pragma unroll
    for (int bi = 0; bi < 8; ++bi) { accs[bi] = 0.f; accw[bi] = 0.f; }

    int e0 = offs[n];
    int deg = offs[n + 1] - e0;

    for (int cb = 0; cb < deg; cb += CHUNK) {
        int cd = deg - cb; if (cd > CHUNK) cd = CHUNK;
        for (int j = tid; j < cd; j += 256) {
            int e = csr[e0 + cb + j];
            srcni_l[j] = node_idx[esrc[e]];
            int rt = erel[e]; if (rt == 0) rt = 1;
            rt_l[j] = rt;
            int et = etim[e]; if (et == 0) et = 1;
            et_l[j] = et;
        }
        __syncthreads();
        for (int idx = tid; idx < cd * DD; idx += 256) {
            int j = idx >> 7, dd = idx & 127;
            er_l[idx] = ldf(ent, (size_t)srcni_l[j] * DD + dd, isf32)
                      + ldf(rel_emb, (size_t)rt_l[j] * DD + dd, isf32);
        }
        __syncthreads();
        for (int j = 0; j < cd; ++j) {
            float erv = er_l[j * DD + d];
            int et = et_l[j];
#pragma unroll
            for (int bi = 0; bi < 8; ++bi) {
                int td = et - bt_r[bi]; if (td < 0) td = -td;
                float tv = ldf(tau_emb, ((size_t)(td + 1) << 7) + d, isf32);
                float g = erv + tv;
                float sc = xi * (g * pjv);
                float p = __expf(sc > 0.f ? sc : 0.01f * sc);
                accs[bi] += p;
                accw[bi] = fmaf(p, g, accw[bi]);
            }
        }
        __syncthreads();
    }

#pragma unroll
    for (int bi = 0; bi < 8; ++bi) {
        float hv = accw[bi] / (accs[bi] + 1e-16f);
        int b = bh * 8 + bi;
        sto(out, ((size_t)n * BB + b) * DD + d, lrelu(hv), isf32);
    }
}

// ---- zero the a_new region of out ----
__global__ void k_zero_a(const int* __restrict__ flag, void* __restrict__ out) {
    int i = blockIdx.x * 256 + threadIdx.x;
    if (i < NN * BB * HH) sto(out, OUT_H_ELEMS + i, 0.f, (*flag > 8));
}

// ---- query + g_head (tiny matmuls), one block per b ----
__global__ void k_ghead(const void* __restrict__ ent, const void* __restrict__ rel,
                        const void* __restrict__ Wc_w, const void* __restrict__ Wc_b,
                        const void* __restrict__ Wn_w, const void* __restrict__ Wn_b,
                        const int* __restrict__ head, const int* __restrict__ relation,
                        const void* __restrict__ out, const int* __restrict__ flag,
                        float* __restrict__ gh) {
    __shared__ float q[DD];
    __shared__ float hn[DD];
    int b = blockIdx.x, k = threadIdx.x;
    int isf32 = (*flag > 8);
    int hb = head[b], rb = relation[b];
    size_t eroff = (size_t)hb * DD, rroff = (size_t)rb * DD;
    size_t woff = (size_t)k * 2 * DD;
    float acc = ldf(Wc_b, k, isf32);
    for (int j = 0; j < DD; ++j) acc += ldf(ent, eroff + j, isf32) * ldf(Wc_w, woff + j, isf32);
    for (int j = 0; j < DD; ++j) acc += ldf(rel, rroff + j, isf32) * ldf(Wc_w, woff + DD + j, isf32);
    q[k] = acc;
    hn[k] = ldf(out, ((size_t)hb * BB + b) * DD + k, isf32);
    __syncthreads();
    float acc2 = ldf(Wn_b, k, isf32);
    for (int j = 0; j < DD; ++j) acc2 += hn[j] * ldf(Wn_w, woff + j, isf32);
    for (int j = 0; j < DD; ++j) acc2 += q[j] * ldf(Wn_w, woff + DD + j, isf32);
    gh[b * DD + k] = acc2;
}

// ---- compact matched (e,b) pairs: src == head[b] ----
__global__ void k_pairs(const int* __restrict__ esrc, const int* __restrict__ head,
                        int* __restrict__ npairs, int* __restrict__ pairs) {
    __shared__ int head_l[BB];
    if (threadIdx.x < BB) head_l[threadIdx.x] = head[threadIdx.x];
    __syncthreads();
    int e = blockIdx.x * 256 + threadIdx.x;
    if (e >= EE) return;
    int s = esrc[e];
    for (int b = 0; b < BB; ++b) {
        if (head_l[b] == s) {
            int idx = atomicAdd(npairs, 1);
            if (idx < MAXP) pairs[idx] = (e << 4) | b;
        }
    }
}

// ---- per-pair scores, lane-parallel: p[h] stored, denom accumulated ----
// block = 128 threads (2 waves); thread d owns dim d; 16-lane segment per head
__global__ void __launch_bounds__(128) k_edgep(
    const int* __restrict__ edst,
    const int* __restrict__ erel, const int* __restrict__ etim,
    const int* __restrict__ head, const int* __restrict__ btime,
    const void* __restrict__ rel_emb, const void* __restrict__ tau_emb,
    const void* __restrict__ ai_w, const void* __restrict__ aj_w,
    const void* __restrict__ iai_w, const void* __restrict__ iaj_w,
    const float* __restrict__ gh, const void* __restrict__ out,
    const int* __restrict__ npairs, const int* __restrict__ pairs,
    const int* __restrict__ flag, float* __restrict__ denom, float* __restrict__ pp) {
    int d = threadIdx.x;
    int isf32 = (*flag > 8);
    int np = *npairs; if (np > MAXP) np = MAXP;
    float aiv = ldf(ai_w, d, isf32), ajv = ldf(aj_w, d, isf32);
    float iaiv = ldf(iai_w, d, isf32), iajv = ldf(iaj_w, d, isf32);
    for (int i = blockIdx.x; i < np; i += gridDim.x) {
        int pr = pairs[i];
        int e = pr >> 4, b = pr & 15;
        int dst = edst[e];
        int rt = erel[e]; if (rt == 0) rt = 1;
        int et = etim[e]; if (et == 0) et = 1;
        int td = et - btime[b]; if (td < 0) td = -td;
        float hev = ldf(rel_emb, (size_t)rt * DD + d, isf32);
        float tav = ldf(tau_emb, (size_t)(td + 1) * DD + d, isf32);
        float gd = gh[b * DD + d];
        bool dh = (dst == head[b]);
        float ges = (dh ? gd : 0.f) + hev + tav;
        float geo = ldf(out, ((size_t)dst * BB + b) * DD + d, isf32) + hev + tav;
        float tsa = (gd * aiv) * (ges * ajv);
        float tsi = (gd * iaiv) * (geo * iajv);
        // reduce within 16-lane segments (heads)
        for (int m = 8; m >= 1; m >>= 1) {
            tsa += __shfl_xor(tsa, m, 64);
            tsi += __shfl_xor(tsi, m, 64);
        }
        if ((d & 15) == 0) {
            int h = d >> 4;
            float p = __expf(lrelu(tsa) + lrelu(tsi));
            pp[i * HH + h] = p;
            atomicAdd(&denom[b * HH + h], p);
        }
    }
}

// ---- scatter a contributions: one thread per (pair,h) ----
__global__ void k_scatter_a(const int* __restrict__ edst,
                            const int* __restrict__ npairs, const int* __restrict__ pairs,
                            const float* __restrict__ pp, const float* __restrict__ denom,
                            const int* __restrict__ flag, void* __restrict__ out) {
    int t = blockIdx.x * 256 + threadIdx.x;
    int np = *npairs; if (np > MAXP) np = MAXP;
    if (t >= np * HH) return;
    int i = t >> 3, h = t & 7;
    int pr = pairs[i];
    int e = pr >> 4, b = pr & 15;
    int dst = edst[e];
    float a = pp[i * HH + h] / (denom[b * HH + h] + 1e-16f);
    size_t idx = OUT_H_ELEMS + ((size_t)dst * BB + b) * HH + h;
    atomicAddF(out, idx, a, (*flag > 8));
}

extern "C" void kernel_launch(void* const* d_in, const int* in_sizes, int n_in,
                              void* d_out, int out_size, void* d_ws, size_t ws_size,
                              hipStream_t stream) {
    const void* ent   = d_in[0];
    const void* rel   = d_in[1];
    const void* tau   = d_in[2];
    const void* Wc_w  = d_in[3];
    const void* Wc_b  = d_in[4];
    const void* Wn_w  = d_in[5];
    const void* Wn_b  = d_in[6];
    const void* ai_w  = d_in[7];
    const void* aj_w  = d_in[8];
    const void* iai_w = d_in[9];
    const void* iaj_w = d_in[10];
    const void* pi_w  = d_in[11];
    const void* pj_w  = d_in[12];
    const int* node_idx = (const int*)d_in[13];
    const int* esrc     = (const int*)d_in[14];
    const int* edst     = (const int*)d_in[15];
    const int* erel     = (const int*)d_in[16];
    const int* etim     = (const int*)d_in[17];
    const int* head     = (const int*)d_in[18];
    const int* relation = (const int*)d_in[19];
    const int* btime    = (const int*)d_in[20];

    char* ws = (char*)d_ws;
    size_t o = 0;
    auto alloc = [&](size_t bytes) -> char* {
        char* p = ws + o;
        o += (bytes + 255) & ~(size_t)255;
        return p;
    };
    int* flag     = (int*)alloc(4);               // zeroed
    int* cnt      = (int*)alloc(NN * 4);          // zeroed (adjacent to flag)
    int* cursor   = (int*)alloc(NN * 4);          // zeroed (adjacent to cnt)
    int* offs     = (int*)alloc((NN + 1) * 4);
    int* csr      = (int*)alloc(EE * 4);
    float* gh     = (float*)alloc(BB * DD * 4);
    float* denom  = (float*)alloc(BB * HH * 4);   // zeroed (512B pad)
    int* npairs   = (int*)alloc(4);               // zeroed (adjacent to denom)
    int* pairs    = (int*)alloc(MAXP * 4);
    float* pp     = (float*)alloc(MAXP * HH * 4);
    // total ws ~420 KB

    size_t cnt_pad = (NN * 4 + 255) & ~(size_t)255;
    hipMemsetAsync(flag, 0, 256 + cnt_pad * 2, stream);   // flag + cnt + cursor
    hipMemsetAsync(denom, 0, 512 + 256, stream);          // denom + npairs

    k_detect<<<1, 256, 0, stream>>>(ent, flag);
    k_count<<<(EE + 255) / 256, 256, 0, stream>>>(edst, cnt);
    k_scan<<<1, 1024, 0, stream>>>(cnt, offs);
    k_scatter<<<(EE + 255) / 256, 256, 0, stream>>>(edst, offs, cursor, csr);

    k_zero_a<<<(NN * BB * HH + 255) / 256, 256, 0, stream>>>(flag, d_out);

    k_hn<<<NN, 256, 0, stream>>>(
        ent, rel, tau, pi_w, pj_w, node_idx, esrc, erel, etim, btime, offs, csr, flag, d_out);

    k_ghead<<<BB, DD, 0, stream>>>(ent, rel, Wc_w, Wc_b, Wn_w, Wn_b,
                                   head, relation, d_out, flag, gh);

    k_pairs<<<(EE + 255) / 256, 256, 0, stream>>>(esrc, head, npairs, pairs);

    k_edgep<<<64, 128, 0, stream>>>(
        edst, erel, etim, head, btime, rel, tau,
        ai_w, aj_w, iai_w, iaj_w, gh, d_out, npairs, pairs, flag, denom, pp);

    k_scatter_a<<<(MAXP * HH + 255) / 256, 256, 0, stream>>>(
        edst, npairs, pairs, pp, denom, flag, d_out);
}